// Round 16
// baseline (88.285 us; speedup 1.0000x reference)
//
#include <hip/hip_runtime.h>
#include <hip/hip_bf16.h>

typedef __attribute__((ext_vector_type(8))) short bf16x8;
typedef __attribute__((ext_vector_type(16))) float f32x16;
typedef __attribute__((ext_vector_type(4))) unsigned int u32x4;

#define CIN   64
#define KOUT  64
#define HH_   128
#define WW_   128
#define HW    (HH_ * WW_)
#define ROWB  4160          // bytes per (hp) row: 130 wp * 32 B
#define TILEB 24960         // 6 rows
#define BUFB  25600         // 25 runs * 1024

__device__ __forceinline__ unsigned short f2bf(float f) {
    return __builtin_bit_cast(unsigned short, __float2bfloat16(f));
}

// wpk layout: [cc][tap][hi][ko][j]  (A-fragment order for mfma_32x32x16_bf16)
__global__ __launch_bounds__(256) void prepack(const float* __restrict__ wgt,
                                               unsigned short* __restrict__ wpk) {
    int i = blockIdx.x * 256 + threadIdx.x;
    if (i >= KOUT * CIN * 9) return;
    int tap = i % 9, rem = i / 9;
    int c = rem % CIN, ko = rem / CIN;
    float v = wgt[((size_t)ko * CIN + c) * 9 + tap];
    int cc = c >> 4, hi = (c >> 3) & 1, j = c & 7;
    wpk[((((size_t)cc * 9 + tap) * 2 + hi) * KOUT + ko) * 8 + j] = f2bf(v);
}

// zero halo rows (hp=0,129) and halo cols (wp=0,129) of the xp image
__global__ __launch_bounds__(256) void xzero(unsigned char* __restrict__ xp) {
    int idx = blockIdx.x * 256 + threadIdx.x;   // one 16B chunk each
    u32x4 z = {0u, 0u, 0u, 0u};
    if (idx < 66560) {                          // rows: 128 ncc * 2 * 260 chunks
        int q = idx % 260, r = idx / 260;
        int hp = (r & 1) ? 129 : 0, ncc = r >> 1;
        *reinterpret_cast<u32x4*>(xp + ((size_t)ncc * 130 + hp) * ROWB + q * 16) = z;
    } else if (idx < 66560 + 65536) {           // cols: 128 ncc *128 hp *2 side *2 half
        int i = idx - 66560;
        int half = i & 1, side = (i >> 1) & 1, hp = ((i >> 2) & 127) + 1, ncc = i >> 9;
        *reinterpret_cast<u32x4*>(xp + ((size_t)ncc * 130 + hp) * ROWB +
                                  (side ? 129 : 0) * 32 + half * 16) = z;
    }
}

// x f32 NCHW -> bf16 swizzled LDS-image: [n][cc][hp][wp][slot]
// slot for (wp,hi) at byte wp*32 + ((hi ^ (wp>>4)) & 1)*16 within the row.
__global__ __launch_bounds__(256) void xprep(const float* __restrict__ x,
                                             unsigned char* __restrict__ xp) {
    const int t = threadIdx.x;
    const int h = blockIdx.x;      // 0..127
    const int n = blockIdx.y;      // 0..31
    const int w = t & 127, g = t >> 7;
    const int wp = w + 1, hp = h + 1;
    const int swz = (wp >> 4) & 1;
    #pragma unroll
    for (int ccq = 0; ccq < 2; ++ccq) {
        const int cc = g * 2 + ccq;
        #pragma unroll
        for (int hi = 0; hi < 2; ++hi) {
            float f[8];
            #pragma unroll
            for (int j = 0; j < 8; ++j)
                f[j] = x[((size_t)(n * 64 + cc * 16 + hi * 8 + j) * 128 + h) * 128 + w];
            u32x4 u;
            #pragma unroll
            for (int q = 0; q < 4; ++q)
                u[q] = (unsigned)f2bf(f[2 * q]) | ((unsigned)f2bf(f[2 * q + 1]) << 16);
            *reinterpret_cast<u32x4*>(xp + ((size_t)(n * 4 + cc) * 130 + hp) * ROWB +
                                      wp * 32 + ((hi ^ swz) & 1) * 16) = u;
        }
    }
}

// main: stage via global_load_lds (linear dest, pre-swizzled source),
// counted vmcnt, two raw barriers per chunk, zero stage-VALU.
__global__ __launch_bounds__(256, 2) void conv_dma(
    const unsigned char* __restrict__ xp, const unsigned short* __restrict__ wpk,
    const float* __restrict__ bias, float* __restrict__ out)
{
    __shared__ __align__(16) unsigned char xs[2][BUFB];

    const int tid  = threadIdx.x;
    const int lane = tid & 63;
    const int wv   = tid >> 6;     // 0..3 = output row within tile
    const int l31  = lane & 31;
    const int hi   = lane >> 5;

    // bijective XCD swizzle (1024 % 8 == 0)
    const int b    = blockIdx.x;
    const int work = (b & 7) * 128 + (b >> 3);
    const int ht   = work & 31;
    const int n    = work >> 5;
    const int h0   = ht * 4;       // tile input rows hp = h0 .. h0+5 (contiguous!)

    // acc init with bias: D row(M=kout) = (p&3)+8*(p>>2)+4*hi, col(N)=l31
    f32x16 acc[2][4];
    #pragma unroll
    for (int mt = 0; mt < 2; ++mt)
        #pragma unroll
        for (int p = 0; p < 16; ++p) {
            float bv = bias[mt * 32 + (p & 3) + 8 * (p >> 2) + 4 * hi];
            #pragma unroll
            for (int nt = 0; nt < 4; ++nt) acc[mt][nt][p] = bv;
        }

    // ds_read byte offsets: addr = buf + (wv+r)*ROWB + soff[s] + nt*1024
    int soff[3];
    #pragma unroll
    for (int s = 0; s < 3; ++s) {
        const int t2 = l31 + s;
        soff[s] = t2 * 32 + ((hi ^ (t2 >> 4)) & 1) * 16;
    }

    auto DMA = [&](int cc, int bufi) {   // 7 runs/wave (runs >24 duplicate 24)
        const unsigned char* tb = xp + ((size_t)(n * 4 + cc) * 130 + h0) * ROWB;
        #pragma unroll
        for (int i = 0; i < 7; ++i) {
            int kk = wv * 7 + i; if (kk > 24) kk = 24;
            __builtin_amdgcn_global_load_lds(
                (const __attribute__((address_space(1))) unsigned int*)
                    (tb + kk * 1024 + lane * 16),
                (__attribute__((address_space(3))) unsigned int*)
                    (&xs[bufi][kk * 1024]),
                16, 0, 0);
        }
    };

    bf16x8 af[9][2];
    auto ALOAD = [&](int cc) {
        #pragma unroll
        for (int tap = 0; tap < 9; ++tap) {
            const size_t wbase = (((size_t)cc * 9 + tap) * 2 + hi) * KOUT;
            af[tap][0] = *reinterpret_cast<const bf16x8*>(&wpk[(wbase + l31) * 8]);
            af[tap][1] = *reinterpret_cast<const bf16x8*>(&wpk[(wbase + 32 + l31) * 8]);
        }
    };

    DMA(0, 0);   // prologue

    #pragma unroll 1
    for (int cc = 0; cc < 4; ++cc) {
        const int bufi = cc & 1;
        ALOAD(cc);                           // 18 loads, queue: [DMA(cc)][A]
        __builtin_amdgcn_sched_barrier(0);
        if (cc < 3) {
            DMA(cc + 1, bufi ^ 1);           // queue: [DMA(cc)][A18][DMA'7]
            __builtin_amdgcn_sched_barrier(0);
            asm volatile("s_waitcnt vmcnt(25)" ::: "memory");  // DMA(cc) drained
        } else {
            __builtin_amdgcn_sched_barrier(0);
            asm volatile("s_waitcnt vmcnt(18)" ::: "memory");
        }
        __builtin_amdgcn_s_barrier();        // buf ready for all waves
        __builtin_amdgcn_sched_barrier(0);

        const unsigned char* bufp = &xs[bufi][0];
        #pragma unroll
        for (int tap = 0; tap < 9; ++tap) {
            const int r = tap / 3, s = tap % 3;
            #pragma unroll
            for (int nt = 0; nt < 4; ++nt) {
                bf16x8 bv = *reinterpret_cast<const bf16x8*>(
                    bufp + (wv + r) * ROWB + soff[s] + nt * 1024);
                acc[0][nt] = __builtin_amdgcn_mfma_f32_32x32x16_bf16(
                    af[tap][0], bv, acc[0][nt], 0, 0, 0);
                acc[1][nt] = __builtin_amdgcn_mfma_f32_32x32x16_bf16(
                    af[tap][1], bv, acc[1][nt], 0, 0, 0);
            }
        }
        __builtin_amdgcn_s_barrier();        // WAR: next DMA may overwrite buf^1
    }

    // epilogue: coalesced nontemporal stores
    float* ob = out + (size_t)n * KOUT * HW + (size_t)(h0 + wv) * WW_;
    #pragma unroll
    for (int mt = 0; mt < 2; ++mt)
        #pragma unroll
        for (int p = 0; p < 16; ++p) {
            const int ko = mt * 32 + (p & 3) + 8 * (p >> 2) + 4 * hi;
            #pragma unroll
            for (int nt = 0; nt < 4; ++nt)
                __builtin_nontemporal_store(acc[mt][nt][p],
                    &ob[(size_t)ko * HW + nt * 32 + l31]);
        }
}

// ---------------- fallback (r12 kernel) if ws too small ------
__global__ __launch_bounds__(256, 2) void conv_mfma(
    const float* __restrict__ x, const unsigned short* __restrict__ wpk,
    const float* __restrict__ bias, float* __restrict__ out)
{
    __shared__ __align__(16) unsigned short xsf[2][6][130][16];
    const int tid  = threadIdx.x;
    const int lane = tid & 63;
    const int wv   = tid >> 6;
    const int l31  = lane & 31;
    const int hi   = lane >> 5;
    const int b    = blockIdx.x;
    const int work = (b & 7) * 128 + (b >> 3);
    const int ht   = work & 31;
    const int n    = work >> 5;
    const int h0   = ht * 4;
    if (tid < 48) {
        int i = tid; int bufi = i / 24; i -= bufi * 24;
        int r = i >> 2, cs = (i >> 1) & 1, g = i & 1;
        u32x4 z = {0u, 0u, 0u, 0u};
        *reinterpret_cast<u32x4*>(&xsf[bufi][r][cs ? 129 : 0][g * 8]) = z;
    }
    f32x16 acc[2][4];
    #pragma unroll
    for (int mt = 0; mt < 2; ++mt)
        #pragma unroll
        for (int p = 0; p < 16; ++p) {
            float bv = bias[mt * 32 + (p & 3) + 8 * (p >> 2) + 4 * hi];
            #pragma unroll
            for (int nt = 0; nt < 4; ++nt) acc[mt][nt][p] = bv;
        }
    const float* xb   = x + (size_t)n * CIN * HW;
    const int    sch  = tid & 1;
    const int    scol = tid >> 1;
    int  hh[6]; bool okr[6];
    #pragma unroll
    for (int r6 = 0; r6 < 6; ++r6) {
        hh[r6] = h0 - 1 + r6; okr[r6] = (hh[r6] >= 0) && (hh[r6] < HH_);
    }
    const int sgp = sch ^ (((scol + 1) >> 2) & 1);
    float rx[6][8];
    auto ISSUE = [&](int cc) {
        #pragma unroll
        for (int r6 = 0; r6 < 6; ++r6)
            #pragma unroll
            for (int e = 0; e < 8; ++e)
                rx[r6][e] = okr[r6]
                    ? xb[(size_t)(cc * 16 + sch * 8 + e) * HW + hh[r6] * WW_ + scol]
                    : 0.f;
    };
    auto WRITE = [&](int bufi) {
        #pragma unroll
        for (int r6 = 0; r6 < 6; ++r6) {
            u32x4 u;
            #pragma unroll
            for (int q = 0; q < 4; ++q)
                u[q] = (unsigned)f2bf(rx[r6][2 * q]) |
                       ((unsigned)f2bf(rx[r6][2 * q + 1]) << 16);
            *reinterpret_cast<u32x4*>(&xsf[bufi][r6][scol + 1][sgp * 8]) = u;
        }
    };
    auto ALOAD1 = [&](int cc, int tap, bf16x8* dst) {
        const size_t wbase = (((size_t)cc * 9 + tap) * 2 + hi) * KOUT;
        dst[0] = *reinterpret_cast<const bf16x8*>(&wpk[(wbase + l31) * 8]);
        dst[1] = *reinterpret_cast<const bf16x8*>(&wpk[(wbase + 32 + l31) * 8]);
    };
    ISSUE(0);
    #pragma unroll 1
    for (int cc = 0; cc < 4; ++cc) {
        WRITE(cc & 1);
        bf16x8 afr[2][2];
        ALOAD1(cc, 0, afr[0]);
        ALOAD1(cc, 1, afr[1]);
        if (cc < 3) ISSUE(cc + 1);
        asm volatile("s_waitcnt lgkmcnt(0)" ::: "memory");
        __builtin_amdgcn_s_barrier();
        asm volatile("" ::: "memory");
        #pragma unroll
        for (int tap = 0; tap < 9; ++tap) {
            const int r = tap / 3, s = tap % 3;
            bf16x8 a0 = afr[tap & 1][0];
            bf16x8 a1 = afr[tap & 1][1];
            if (tap + 2 < 9) ALOAD1(cc, tap + 2, afr[tap & 1]);
            #pragma unroll
            for (int nt = 0; nt < 4; ++nt) {
                const int lcol = nt * 32 + l31 + s;
                const int gp   = hi ^ ((lcol >> 2) & 1);
                bf16x8 bv = *reinterpret_cast<const bf16x8*>(
                    &xsf[cc & 1][wv + r][lcol][gp * 8]);
                acc[0][nt] = __builtin_amdgcn_mfma_f32_32x32x16_bf16(
                    a0, bv, acc[0][nt], 0, 0, 0);
                acc[1][nt] = __builtin_amdgcn_mfma_f32_32x32x16_bf16(
                    a1, bv, acc[1][nt], 0, 0, 0);
            }
        }
    }
    float* ob = out + (size_t)n * KOUT * HW + (size_t)(h0 + wv) * WW_;
    #pragma unroll
    for (int mt = 0; mt < 2; ++mt)
        #pragma unroll
        for (int p = 0; p < 16; ++p) {
            const int ko = mt * 32 + (p & 3) + 8 * (p >> 2) + 4 * hi;
            #pragma unroll
            for (int nt = 0; nt < 4; ++nt)
                __builtin_nontemporal_store(acc[mt][nt][p],
                    &ob[(size_t)ko * HW + nt * 32 + l31]);
        }
}

extern "C" void kernel_launch(void* const* d_in, const int* in_sizes, int n_in,
                              void* d_out, int out_size, void* d_ws, size_t ws_size,
                              hipStream_t stream) {
    const float* x    = (const float*)d_in[0];
    const float* wgt  = (const float*)d_in[1];
    const float* bias = (const float*)d_in[2];
    float* out        = (float*)d_out;

    unsigned short* wpk = (unsigned short*)d_ws;                 // 73728 B
    unsigned char*  xpb = (unsigned char*)d_ws + 131072;         // swizzled image
    const size_t xp_sz  = (size_t)32 * 4 * 130 * ROWB;           // 69.2 MB
    const size_t need   = 131072 + xp_sz + 1024;                 // + overread pad

    prepack<<<dim3(144), dim3(256), 0, stream>>>(wgt, wpk);
    if (ws_size >= need) {
        xzero<<<dim3(517), dim3(256), 0, stream>>>(xpb);
        xprep<<<dim3(128, 32), dim3(256), 0, stream>>>(x, xpb);
        conv_dma<<<dim3(1024), dim3(256), 0, stream>>>(xpb, wpk, bias, out);
    } else {
        conv_mfma<<<dim3(1024), dim3(256), 0, stream>>>(x, wpk, bias, out);
    }
}